// Round 5
// baseline (315.650 us; speedup 1.0000x reference)
//
#include <hip/hip_runtime.h>
#include <hip/hip_bf16.h>

// ---------------------------------------------------------------------------
// AdaptiveEmbedding: 3-cluster adaptive input embedding.
//   ids in [0,20000)      -> emb0[id] (1024), padding row 0 is zero
//   ids in [20000,60000)  -> proj1(1024x256) @ emb1[id-20000]
//   ids in [60000,128000) -> proj2(1024x64)  @ emb2[id-60000]
// Scaled by sqrt(1024)=32. Each out row written exactly once.
//
// R7 -> R8: R7 doubled occupancy (20->47%) but got SLOWER (83.8->96.4us) ->
// not occupancy-limited. All pipes idle at any occupancy => REQUEST-rate
// bound: C-stores were store_dword (4B/lane, 4 scattered 64-B segs/instr,
// ~2M sub-line write reqs) and B-loads were 16B/lane at 512-B stride (16
// scattered segs/instr, ~3.7M reqs). Fix: (a) revert to M=32/8-wave tiles
// (halves B traffic vs R7); (b) prep packs B in MFMA-fragment order so each
// B load is one lane-contiguous 1KB dwordx4 (full lines); (c) epilogue
// transposes acc through per-wave LDS scratch and stores lane-contiguous
// float4 (512B/row-seg, 4x fewer store instrs, full lines). LDS: A-tile and
// transpose scratch share one union buffer (67.9 KB) -> 2 blocks/CU at
// __launch_bounds__(512,4) (VGPR capped 128).
// ---------------------------------------------------------------------------

typedef __attribute__((ext_vector_type(4))) float        float4v;
typedef __attribute__((ext_vector_type(8))) short        short8;
typedef __attribute__((ext_vector_type(2))) unsigned int uint2v;
typedef __attribute__((ext_vector_type(2))) int          int2v;

#define D_MODEL 1024

__device__ __forceinline__ short f2bf(float x) {
    // round-to-nearest-even f32 -> bf16 (inputs are finite)
    unsigned u = __builtin_bit_cast(unsigned, x);
    unsigned r = u + 0x7fffu + ((u >> 16) & 1u);
    return (short)(r >> 16);
}

__device__ __forceinline__ short8 cvt8(float4v a, float4v b) {
    short8 r;
    r[0] = f2bf(a[0]); r[1] = f2bf(a[1]); r[2] = f2bf(a[2]); r[3] = f2bf(a[3]);
    r[4] = f2bf(b[0]); r[5] = f2bf(b[1]); r[6] = f2bf(b[2]); r[7] = f2bf(b[3]);
    return r;
}

__device__ __forceinline__ uint2v pack4(float4v v) {
    uint2v r;
    r[0] = (unsigned)(unsigned short)f2bf(v[0]) | ((unsigned)(unsigned short)f2bf(v[1]) << 16);
    r[1] = (unsigned)(unsigned short)f2bf(v[2]) | ((unsigned)(unsigned short)f2bf(v[3]) << 16);
    return r;
}

// ------------------ partition (3 int2 lists) + proj->bf16 fragment packing --
// 1024-thread blocks.
// blocks [0, pb)        : partition ids into l0/l1/l2 as int2 {tok, loc}.
// blocks [pb, pb+32)    : pack proj1 (1024x256) into MFMA-fragment order
// blocks [pb+32, pb+40) : pack proj2 (1024x64)
// Fragment order: frag16_idx = ((nt*(K/32) + ks32)*64 + lane); the short8 at
// that index holds B[n = nt*16 + (lane&15)][k = ks32*32 + (lane>>4)*8 + j],
// j=0..7 -- exactly the per-lane MFMA B fragment, so the GEMM's B load is
// lane-contiguous (1KB/wave-instr, full 128-B lines).
__global__ __launch_bounds__(1024)
void prep_k(const int* __restrict__ ids, int n, int pb,
            int* __restrict__ cnt,
            int2v* __restrict__ l0, int2v* __restrict__ l1, int2v* __restrict__ l2,
            const float* __restrict__ proj1, const float* __restrict__ proj2,
            short8* __restrict__ p1bf, short8* __restrict__ p2bf)
{
    const int b = blockIdx.x;
    if (b >= pb) {
        int bb = b - pb;
        if (bb < 32) {                       // proj1: 32768 frags (K=256, KS=8)
            int t    = bb * 1024 + threadIdx.x;
            int lane = t & 63;
            int ks32 = (t >> 6) & 7;
            int nt   = t >> 9;               // 0..63
            int nrow = nt * 16 + (lane & 15);
            int k0   = ks32 * 32 + (lane >> 4) * 8;
            const float* s = proj1 + nrow * 256 + k0;
            p1bf[t] = cvt8(*(const float4v*)s, *(const float4v*)(s + 4));
        } else {                             // proj2: 8192 frags (K=64, KS=2)
            int t    = (bb - 32) * 1024 + threadIdx.x;
            int lane = t & 63;
            int ks32 = (t >> 6) & 1;
            int nt   = t >> 7;               // 0..63
            int nrow = nt * 16 + (lane & 15);
            int k0   = ks32 * 32 + (lane >> 4) * 8;
            const float* s = proj2 + nrow * 64 + k0;
            p2bf[t] = cvt8(*(const float4v*)s, *(const float4v*)(s + 4));
        }
        return;
    }

    __shared__ int s_wcnt[16][3];    // per-wave counts
    __shared__ int s_wbase[16][3];   // exclusive scan over waves
    __shared__ int s_base[3];        // block's global base per cluster

    const int tid  = threadIdx.x;
    const int wave = tid >> 6;       // 0..15
    const int lane = tid & 63;
    const int i    = b * 1024 + tid;

    int id = (i < n) ? ids[i] : -1;
    bool is0 = (i < n) && (id < 20000);
    bool is1 = (i < n) && (id >= 20000) && (id < 60000);
    bool is2 = (i < n) && (id >= 60000);
    unsigned long long ltmask = (lane == 0) ? 0ull : (~0ull >> (64 - lane));

    unsigned long long m0 = __ballot(is0);
    unsigned long long m1 = __ballot(is1);
    unsigned long long m2 = __ballot(is2);
    if (lane == 0) {
        s_wcnt[wave][0] = __popcll(m0);
        s_wcnt[wave][1] = __popcll(m1);
        s_wcnt[wave][2] = __popcll(m2);
    }
    __syncthreads();

    if (tid < 3) {
        const int c = tid;
        int run = 0;
#pragma unroll
        for (int w = 0; w < 16; w++) { s_wbase[w][c] = run; run += s_wcnt[w][c]; }
        // counter mapping: cluster1->cnt[0], cluster2->cnt[1], cluster0->cnt[2]
        const int gidx = (c == 0) ? 2 : (c - 1);
        s_base[c] = atomicAdd(&cnt[gidx], run);
    }
    __syncthreads();

    if (is0) l0[s_base[0] + s_wbase[wave][0] + __popcll(m0 & ltmask)] = (int2v){i, id};
    if (is1) l1[s_base[1] + s_wbase[wave][1] + __popcll(m1 & ltmask)] = (int2v){i, id - 20000};
    if (is2) l2[s_base[2] + s_wbase[wave][2] + __popcll(m2 & ltmask)] = (int2v){i, id - 60000};
}

// -------------------------- projected-cluster GEMM tile ---------------------
// Tile: 32 gathered tokens x 1024 dims, 8 waves (512 thr). Wave w owns dims
// [w*128, w*128+128) = global n-tiles w*8 .. w*8+7.
// A (32 x K) LDS-staged coalesced, fp32->bf16 on stage, row stride K+8.
// B loads are fragment-packed: one lane-contiguous short8 (1KB/wave-instr).
// Epilogue: acc -> per-wave LDS scratch (16x132 f32) -> lane-contiguous
// float4 stores (2 token rows x 512B per wave-instr, full lines).
// MFMA 16x16x32 bf16 fragment layouts (verified m89 mappings):
//   A: lane holds A[m = lane&15][k = (lane>>4)*8 + j], j=0..7
//   B: lane holds B[k = (lane>>4)*8 + j][n = lane&15]
//   D: acc[reg r] = D[row = (lane>>4)*4 + r][col = lane&15]
template<int K>
__device__ __forceinline__
void gemm_tile(int tile,
               const float* __restrict__ table,    // [rows, K] fp32
               const short8* __restrict__ pbf,     // fragment-packed bf16
               const int2v* __restrict__ list,     // {tok, loc}
               int count,
               float* __restrict__ out,
               int2v* s_tl, short* s_a, float* s_t)
{
    constexpr int PK = K + 8;          // padded LDS A row stride (shorts)
    constexpr int KS = K / 32;         // k-steps
    const int m_base = tile * 32;
    const int tid = threadIdx.x;
    if (tid < 32) {
        int m = m_base + tid;
        s_tl[tid] = (m < count) ? list[m] : (int2v){-1, 0};
    }
    __syncthreads();

    // ---- stage A: 32 rows x K fp32 -> bf16 LDS. 16 thr/row, coalesced.
    {
        const int row = tid >> 4;                       // 0..31
        const int c   = tid & 15;
        const float* src = s_tl ? table + (size_t)s_tl[row][1] * K + c * (K / 16) : nullptr;
        short*       dst = s_a + row * PK + c * (K / 16);
        if constexpr (K == 256) {                       // 16 floats / thread
            const float4v* s4 = (const float4v*)src;
            float4v f0 = s4[0], f1 = s4[1], f2 = s4[2], f3 = s4[3];
            uint2v* d2 = (uint2v*)dst;
            d2[0] = pack4(f0); d2[1] = pack4(f1);
            d2[2] = pack4(f2); d2[3] = pack4(f3);
        } else {                                        // K == 64: 4 floats
            float4v f0 = *(const float4v*)src;
            *(uint2v*)dst = pack4(f0);
        }
    }
    __syncthreads();

    const int lane = tid & 63;
    const int wave = tid >> 6;     // 0..7
    const int col  = lane & 15;
    const int quad = lane >> 4;    // 0..3

    const short* arow0 = s_a + col * PK        + quad * 8;
    const short* arow1 = s_a + (col + 16) * PK + quad * 8;

    float4v acc0[8], acc1[8];
#pragma unroll
    for (int i = 0; i < 8; i++) {
        acc0[i] = (float4v){0.f, 0.f, 0.f, 0.f};
        acc1[i] = (float4v){0.f, 0.f, 0.f, 0.f};
    }

#pragma unroll
    for (int ks32 = 0; ks32 < KS; ks32++) {
        short8 a0 = *(const short8*)(arow0 + ks32 * 32);   // ds_read_b128
        short8 a1 = *(const short8*)(arow1 + ks32 * 32);
        const short8* bp = pbf + ((size_t)(wave * 8) * KS + ks32) * 64 + lane;
#pragma unroll
        for (int nt = 0; nt < 8; nt++) {
            short8 b = bp[(size_t)nt * KS * 64];   // lane-contiguous 1KB load
            acc0[nt] = __builtin_amdgcn_mfma_f32_16x16x32_bf16(a0, b, acc0[nt], 0, 0, 0);
            acc1[nt] = __builtin_amdgcn_mfma_f32_16x16x32_bf16(a1, b, acc1[nt], 0, 0, 0);
        }
    }

    // ---- epilogue: transpose via per-wave LDS scratch, vector stores.
    __syncthreads();               // all waves done reading s_a (aliases s_t)
    float* tsc = s_t + wave * (16 * 132);
    const int c4 = (lane & 31) * 4;
    const int half = lane >> 5;

    // group 0: tokens m_base+0..15
#pragma unroll
    for (int nt = 0; nt < 8; nt++)
#pragma unroll
        for (int r = 0; r < 4; r++)
            tsc[(quad * 4 + r) * 132 + nt * 16 + col] = acc0[nt][r] * 32.0f;
    __syncthreads();
#pragma unroll
    for (int s = 0; s < 8; s++) {
        int R = s * 2 + half;
        float4v v = *(const float4v*)&tsc[R * 132 + c4];
        if (m_base + R < count) {
            int tok = s_tl[R][0];
            *(float4v*)(out + (size_t)tok * D_MODEL + wave * 128 + c4) = v;
        }
    }
    __syncthreads();

    // group 1: tokens m_base+16..31
#pragma unroll
    for (int nt = 0; nt < 8; nt++)
#pragma unroll
        for (int r = 0; r < 4; r++)
            tsc[(quad * 4 + r) * 132 + nt * 16 + col] = acc1[nt][r] * 32.0f;
    __syncthreads();
#pragma unroll
    for (int s = 0; s < 8; s++) {
        int R = s * 2 + half;
        float4v v = *(const float4v*)&tsc[R * 132 + c4];
        if (m_base + 16 + R < count) {
            int tok = s_tl[16 + R][0];
            *(float4v*)(out + (size_t)tok * D_MODEL + wave * 128 + c4) = v;
        }
    }
    __syncthreads();   // s_tl / s_buf reused by next grid-stride iteration
}

// -------------------------- cluster-0 copy item (8 rows / 512 thr) ----------
__device__ __forceinline__
void copy_item(int item, const int2v* __restrict__ l0, int count0,
               const float* __restrict__ emb0, float* __restrict__ out)
{
    int r = item * 8 + (threadIdx.x >> 6);       // 8 rows per item
    if (r < count0) {
        int2v tl = l0[r];                        // {tok, id} - one 8B load
        const float4v* src = (const float4v*)(emb0 + (size_t)tl[1] * D_MODEL);
        float4v*       dst = (float4v*)(out + (size_t)tl[0] * D_MODEL);
        int c = threadIdx.x & 63;
        // 4 independent load chains per thread (row is 256 float4s)
        float4v v0 = src[c], v1 = src[c + 64], v2 = src[c + 128], v3 = src[c + 192];
        dst[c]       = v0 * 32.0f;
        dst[c + 64]  = v1 * 32.0f;
        dst[c + 128] = v2 * 32.0f;
        dst[c + 192] = v3 * 32.0f;
    }
}

// -------------------------- fused consumer ----------------------------------
// One grid-stride kernel over a runtime work-list:
//   items [0, t1)          : cluster-1 GEMM tiles (K=256)  -- long poles first
//   items [t1, t1+t2)      : cluster-2 GEMM tiles (K=64)
//   items [t1+t2, total)   : cluster-0 8-row copies
// All items write disjoint out rows; lists/cnt/packed-B produced by prep_k.
__global__ __launch_bounds__(512, 4)
void fused_main(const float* __restrict__ emb0,
                const float* __restrict__ emb1,
                const float* __restrict__ emb2,
                const short8* __restrict__ p1bf,
                const short8* __restrict__ p2bf,
                const int2v* __restrict__ l0,
                const int2v* __restrict__ l1,
                const int2v* __restrict__ l2,
                const int* __restrict__ cnt,
                float* __restrict__ out)
{
    __shared__ int2v s_tl[32];
    __shared__ char  s_buf[8 * 16 * 132 * 4];   // 67.6 KB: A-tile U transpose
    short* s_a = (short*)s_buf;
    float* s_t = (float*)s_buf;

    const int c1 = cnt[0];
    const int c2 = cnt[1];
    const int c0 = cnt[2];
    const int t1 = (c1 + 31) >> 5;
    const int t2 = (c2 + 31) >> 5;
    const int tc = (c0 + 7) >> 3;
    const int total = t1 + t2 + tc;

    for (int w = blockIdx.x; w < total; w += gridDim.x) {
        if (w < t1) {
            gemm_tile<256>(w, emb1, p1bf, l1, c1, out, s_tl, s_a, s_t);
        } else if (w < t1 + t2) {
            gemm_tile<64>(w - t1, emb2, p2bf, l2, c2, out, s_tl, s_a, s_t);
        } else {
            copy_item(w - t1 - t2, l0, c0, emb0, out);
        }
    }
}

// ---------------------------------------------------------------------------
extern "C" void kernel_launch(void* const* d_in, const int* in_sizes, int n_in,
                              void* d_out, int out_size, void* d_ws, size_t ws_size,
                              hipStream_t stream)
{
    const int*   ids   = (const int*)  d_in[0];
    const float* emb0  = (const float*)d_in[1];
    const float* emb1  = (const float*)d_in[2];
    const float* emb2  = (const float*)d_in[3];
    const float* proj1 = (const float*)d_in[4];
    const float* proj2 = (const float*)d_in[5];
    float*       out   = (float*)d_out;
    const int n = in_sizes[0];                 // 32768 tokens

    // ws layout: [0,256) counters | l0,l1,l2 (n int2 each) | p1bf | p2bf
    int*   cnt  = (int*)d_ws;
    int2v* l0   = (int2v*)((char*)d_ws + 256);
    int2v* l1   = l0 + n;
    int2v* l2   = l1 + n;
    size_t poff = (256 + (size_t)3 * n * 8 + 255) & ~(size_t)255;
    short8* p1bf = (short8*)((char*)d_ws + poff);
    short8* p2bf = p1bf + 32768;               // p1: 32768 frags (512 KB)

    const int pb = (n + 1023) / 1024;          // partition blocks (1024 thr)

    hipMemsetAsync(cnt, 0, 4 * sizeof(int), stream);
    prep_k<<<pb + 32 + 8, 1024, 0, stream>>>(ids, n, pb, cnt, l0, l1, l2,
                                             proj1, proj2, p1bf, p2bf);
    fused_main<<<2048, 512, 0, stream>>>(emb0, emb1, emb2,
                                         p1bf, p2bf, l0, l1, l2, cnt, out);
}

// Round 6
// 256.888 us; speedup vs baseline: 1.2287x; 1.2287x over previous
//
#include <hip/hip_runtime.h>
#include <hip/hip_bf16.h>

// ---------------------------------------------------------------------------
// AdaptiveEmbedding: 3-cluster adaptive input embedding.
//   ids in [0,20000)      -> emb0[id] (1024), padding row 0 is zero
//   ids in [20000,60000)  -> proj1(1024x256) @ emb1[id-20000]
//   ids in [60000,128000) -> proj2(1024x64)  @ emb2[id-60000]
// Scaled by sqrt(1024)=32. Each out row written exactly once.
//
// R8 -> R9: R8's __launch_bounds__(512,4) made the compiler cap VGPR at 64;
// with 64 f32 accumulators live across the K-loop that forced acc to scratch
// -> WRITE_SIZE 147->570MB, FETCH 27->73MB (spill traffic), 96->137us.
// Fix: plain __launch_bounds__(512) (R6 got VGPR=128, no spill, with the
// same acc structure). Keeps R8's two real changes at sane pressure:
//   (a) B pre-packed in MFMA-fragment order -> B load = lane-contiguous 1KB;
//   (b) epilogue transposes acc via per-wave LDS scratch -> float4 stores
//       (512B contiguous per wave-instr, full lines, 4x fewer store instrs).
// ---------------------------------------------------------------------------

typedef __attribute__((ext_vector_type(4))) float        float4v;
typedef __attribute__((ext_vector_type(8))) short        short8;
typedef __attribute__((ext_vector_type(2))) unsigned int uint2v;
typedef __attribute__((ext_vector_type(2))) int          int2v;

#define D_MODEL 1024

__device__ __forceinline__ short f2bf(float x) {
    // round-to-nearest-even f32 -> bf16 (inputs are finite)
    unsigned u = __builtin_bit_cast(unsigned, x);
    unsigned r = u + 0x7fffu + ((u >> 16) & 1u);
    return (short)(r >> 16);
}

__device__ __forceinline__ short8 cvt8(float4v a, float4v b) {
    short8 r;
    r[0] = f2bf(a[0]); r[1] = f2bf(a[1]); r[2] = f2bf(a[2]); r[3] = f2bf(a[3]);
    r[4] = f2bf(b[0]); r[5] = f2bf(b[1]); r[6] = f2bf(b[2]); r[7] = f2bf(b[3]);
    return r;
}

__device__ __forceinline__ uint2v pack4(float4v v) {
    uint2v r;
    r[0] = (unsigned)(unsigned short)f2bf(v[0]) | ((unsigned)(unsigned short)f2bf(v[1]) << 16);
    r[1] = (unsigned)(unsigned short)f2bf(v[2]) | ((unsigned)(unsigned short)f2bf(v[3]) << 16);
    return r;
}

// ------------------ partition (3 int2 lists) + proj->bf16 fragment packing --
// 1024-thread blocks.
// blocks [0, pb)        : partition ids into l0/l1/l2 as int2 {tok, loc}.
// blocks [pb, pb+32)    : pack proj1 (1024x256) into MFMA-fragment order
// blocks [pb+32, pb+40) : pack proj2 (1024x64)
// Fragment order: frag16_idx = ((nt*(K/32) + ks32)*64 + lane); the short8 at
// that index holds B[n = nt*16 + (lane&15)][k = ks32*32 + (lane>>4)*8 + j],
// j=0..7 -- exactly the per-lane MFMA B fragment, so the GEMM's B load is
// lane-contiguous (1KB/wave-instr, full 128-B lines).
__global__ __launch_bounds__(1024)
void prep_k(const int* __restrict__ ids, int n, int pb,
            int* __restrict__ cnt,
            int2v* __restrict__ l0, int2v* __restrict__ l1, int2v* __restrict__ l2,
            const float* __restrict__ proj1, const float* __restrict__ proj2,
            short8* __restrict__ p1bf, short8* __restrict__ p2bf)
{
    const int b = blockIdx.x;
    if (b >= pb) {
        int bb = b - pb;
        if (bb < 32) {                       // proj1: 32768 frags (K=256, KS=8)
            int t    = bb * 1024 + threadIdx.x;
            int lane = t & 63;
            int ks32 = (t >> 6) & 7;
            int nt   = t >> 9;               // 0..63
            int nrow = nt * 16 + (lane & 15);
            int k0   = ks32 * 32 + (lane >> 4) * 8;
            const float* s = proj1 + nrow * 256 + k0;
            p1bf[t] = cvt8(*(const float4v*)s, *(const float4v*)(s + 4));
        } else {                             // proj2: 8192 frags (K=64, KS=2)
            int t    = (bb - 32) * 1024 + threadIdx.x;
            int lane = t & 63;
            int ks32 = (t >> 6) & 1;
            int nt   = t >> 7;               // 0..63
            int nrow = nt * 16 + (lane & 15);
            int k0   = ks32 * 32 + (lane >> 4) * 8;
            const float* s = proj2 + nrow * 64 + k0;
            p2bf[t] = cvt8(*(const float4v*)s, *(const float4v*)(s + 4));
        }
        return;
    }

    __shared__ int s_wcnt[16][3];    // per-wave counts
    __shared__ int s_wbase[16][3];   // exclusive scan over waves
    __shared__ int s_base[3];        // block's global base per cluster

    const int tid  = threadIdx.x;
    const int wave = tid >> 6;       // 0..15
    const int lane = tid & 63;
    const int i    = b * 1024 + tid;

    int id = (i < n) ? ids[i] : -1;
    bool is0 = (i < n) && (id < 20000);
    bool is1 = (i < n) && (id >= 20000) && (id < 60000);
    bool is2 = (i < n) && (id >= 60000);
    unsigned long long ltmask = (lane == 0) ? 0ull : (~0ull >> (64 - lane));

    unsigned long long m0 = __ballot(is0);
    unsigned long long m1 = __ballot(is1);
    unsigned long long m2 = __ballot(is2);
    if (lane == 0) {
        s_wcnt[wave][0] = __popcll(m0);
        s_wcnt[wave][1] = __popcll(m1);
        s_wcnt[wave][2] = __popcll(m2);
    }
    __syncthreads();

    if (tid < 3) {
        const int c = tid;
        int run = 0;
#pragma unroll
        for (int w = 0; w < 16; w++) { s_wbase[w][c] = run; run += s_wcnt[w][c]; }
        // counter mapping: cluster1->cnt[0], cluster2->cnt[1], cluster0->cnt[2]
        const int gidx = (c == 0) ? 2 : (c - 1);
        s_base[c] = atomicAdd(&cnt[gidx], run);
    }
    __syncthreads();

    if (is0) l0[s_base[0] + s_wbase[wave][0] + __popcll(m0 & ltmask)] = (int2v){i, id};
    if (is1) l1[s_base[1] + s_wbase[wave][1] + __popcll(m1 & ltmask)] = (int2v){i, id - 20000};
    if (is2) l2[s_base[2] + s_wbase[wave][2] + __popcll(m2 & ltmask)] = (int2v){i, id - 60000};
}

// -------------------------- projected-cluster GEMM tile ---------------------
// Tile: 32 gathered tokens x 1024 dims, 8 waves (512 thr). Wave w owns dims
// [w*128, w*128+128) = global n-tiles w*8 .. w*8+7.
// A (32 x K) LDS-staged coalesced, fp32->bf16 on stage, row stride K+8.
// B loads are fragment-packed: one lane-contiguous short8 (1KB/wave-instr).
// Epilogue: acc -> per-wave LDS scratch (16x132 f32) -> lane-contiguous
// float4 stores (2 token rows x 512B per wave-instr, full lines).
// MFMA 16x16x32 bf16 fragment layouts (verified m89 mappings):
//   A: lane holds A[m = lane&15][k = (lane>>4)*8 + j], j=0..7
//   B: lane holds B[k = (lane>>4)*8 + j][n = lane&15]
//   D: acc[reg r] = D[row = (lane>>4)*4 + r][col = lane&15]
template<int K>
__device__ __forceinline__
void gemm_tile(int tile,
               const float* __restrict__ table,    // [rows, K] fp32
               const short8* __restrict__ pbf,     // fragment-packed bf16
               const int2v* __restrict__ list,     // {tok, loc}
               int count,
               float* __restrict__ out,
               int2v* s_tl, short* s_a, float* s_t)
{
    constexpr int PK = K + 8;          // padded LDS A row stride (shorts)
    constexpr int KS = K / 32;         // k-steps
    const int m_base = tile * 32;
    const int tid = threadIdx.x;
    if (tid < 32) {
        int m = m_base + tid;
        s_tl[tid] = (m < count) ? list[m] : (int2v){-1, 0};
    }
    __syncthreads();

    // ---- stage A: 32 rows x K fp32 -> bf16 LDS. 16 thr/row, coalesced.
    {
        const int row = tid >> 4;                       // 0..31
        const int c   = tid & 15;
        const float* src = table + (size_t)s_tl[row][1] * K + c * (K / 16);
        short*       dst = s_a + row * PK + c * (K / 16);
        if constexpr (K == 256) {                       // 16 floats / thread
            const float4v* s4 = (const float4v*)src;
            float4v f0 = s4[0], f1 = s4[1], f2 = s4[2], f3 = s4[3];
            uint2v* d2 = (uint2v*)dst;
            d2[0] = pack4(f0); d2[1] = pack4(f1);
            d2[2] = pack4(f2); d2[3] = pack4(f3);
        } else {                                        // K == 64: 4 floats
            float4v f0 = *(const float4v*)src;
            *(uint2v*)dst = pack4(f0);
        }
    }
    __syncthreads();

    const int lane = tid & 63;
    const int wave = tid >> 6;     // 0..7
    const int col  = lane & 15;
    const int quad = lane >> 4;    // 0..3

    const short* arow0 = s_a + col * PK        + quad * 8;
    const short* arow1 = s_a + (col + 16) * PK + quad * 8;

    float4v acc0[8], acc1[8];
#pragma unroll
    for (int i = 0; i < 8; i++) {
        acc0[i] = (float4v){0.f, 0.f, 0.f, 0.f};
        acc1[i] = (float4v){0.f, 0.f, 0.f, 0.f};
    }

#pragma unroll
    for (int ks32 = 0; ks32 < KS; ks32++) {
        short8 a0 = *(const short8*)(arow0 + ks32 * 32);   // ds_read_b128
        short8 a1 = *(const short8*)(arow1 + ks32 * 32);
        const short8* bp = pbf + ((size_t)(wave * 8) * KS + ks32) * 64 + lane;
#pragma unroll
        for (int nt = 0; nt < 8; nt++) {
            short8 b = bp[(size_t)nt * KS * 64];   // lane-contiguous 1KB load
            acc0[nt] = __builtin_amdgcn_mfma_f32_16x16x32_bf16(a0, b, acc0[nt], 0, 0, 0);
            acc1[nt] = __builtin_amdgcn_mfma_f32_16x16x32_bf16(a1, b, acc1[nt], 0, 0, 0);
        }
    }

    // ---- epilogue: transpose via per-wave LDS scratch, vector stores.
    __syncthreads();               // all waves done reading s_a (aliases s_t)
    float* tsc = s_t + wave * (16 * 132);
    const int c4 = (lane & 31) * 4;
    const int half = lane >> 5;

    // group 0: tokens m_base+0..15
#pragma unroll
    for (int nt = 0; nt < 8; nt++)
#pragma unroll
        for (int r = 0; r < 4; r++)
            tsc[(quad * 4 + r) * 132 + nt * 16 + col] = acc0[nt][r] * 32.0f;
    __syncthreads();
#pragma unroll
    for (int s = 0; s < 8; s++) {
        int R = s * 2 + half;
        float4v v = *(const float4v*)&tsc[R * 132 + c4];
        if (m_base + R < count) {
            int tok = s_tl[R][0];
            *(float4v*)(out + (size_t)tok * D_MODEL + wave * 128 + c4) = v;
        }
    }
    __syncthreads();

    // group 1: tokens m_base+16..31
#pragma unroll
    for (int nt = 0; nt < 8; nt++)
#pragma unroll
        for (int r = 0; r < 4; r++)
            tsc[(quad * 4 + r) * 132 + nt * 16 + col] = acc1[nt][r] * 32.0f;
    __syncthreads();
#pragma unroll
    for (int s = 0; s < 8; s++) {
        int R = s * 2 + half;
        float4v v = *(const float4v*)&tsc[R * 132 + c4];
        if (m_base + 16 + R < count) {
            int tok = s_tl[16 + R][0];
            *(float4v*)(out + (size_t)tok * D_MODEL + wave * 128 + c4) = v;
        }
    }
    __syncthreads();   // s_tl / s_buf reused by next grid-stride iteration
}

// -------------------------- cluster-0 copy item (8 rows / 512 thr) ----------
__device__ __forceinline__
void copy_item(int item, const int2v* __restrict__ l0, int count0,
               const float* __restrict__ emb0, float* __restrict__ out)
{
    int r = item * 8 + (threadIdx.x >> 6);       // 8 rows per item
    if (r < count0) {
        int2v tl = l0[r];                        // {tok, id} - one 8B load
        const float4v* src = (const float4v*)(emb0 + (size_t)tl[1] * D_MODEL);
        float4v*       dst = (float4v*)(out + (size_t)tl[0] * D_MODEL);
        int c = threadIdx.x & 63;
        // 4 independent load chains per thread (row is 256 float4s)
        float4v v0 = src[c], v1 = src[c + 64], v2 = src[c + 128], v3 = src[c + 192];
        dst[c]       = v0 * 32.0f;
        dst[c + 64]  = v1 * 32.0f;
        dst[c + 128] = v2 * 32.0f;
        dst[c + 192] = v3 * 32.0f;
    }
}

// -------------------------- fused consumer ----------------------------------
// One grid-stride kernel over a runtime work-list:
//   items [0, t1)          : cluster-1 GEMM tiles (K=256)  -- long poles first
//   items [t1, t1+t2)      : cluster-2 GEMM tiles (K=64)
//   items [t1+t2, total)   : cluster-0 8-row copies
// All items write disjoint out rows; lists/cnt/packed-B produced by prep_k.
// Plain __launch_bounds__(512): R6 showed the compiler picks VGPR=128 for
// this acc structure (no spill); adding a min-waves arg (R8) forced VGPR=64
// and spilled the 64 accumulators to scratch (+420MB HBM writes).
__global__ __launch_bounds__(512)
void fused_main(const float* __restrict__ emb0,
                const float* __restrict__ emb1,
                const float* __restrict__ emb2,
                const short8* __restrict__ p1bf,
                const short8* __restrict__ p2bf,
                const int2v* __restrict__ l0,
                const int2v* __restrict__ l1,
                const int2v* __restrict__ l2,
                const int* __restrict__ cnt,
                float* __restrict__ out)
{
    __shared__ int2v s_tl[32];
    __shared__ char  s_buf[8 * 16 * 132 * 4];   // 67.6 KB: A-tile U transpose
    short* s_a = (short*)s_buf;
    float* s_t = (float*)s_buf;

    const int c1 = cnt[0];
    const int c2 = cnt[1];
    const int c0 = cnt[2];
    const int t1 = (c1 + 31) >> 5;
    const int t2 = (c2 + 31) >> 5;
    const int tc = (c0 + 7) >> 3;
    const int total = t1 + t2 + tc;

    for (int w = blockIdx.x; w < total; w += gridDim.x) {
        if (w < t1) {
            gemm_tile<256>(w, emb1, p1bf, l1, c1, out, s_tl, s_a, s_t);
        } else if (w < t1 + t2) {
            gemm_tile<64>(w - t1, emb2, p2bf, l2, c2, out, s_tl, s_a, s_t);
        } else {
            copy_item(w - t1 - t2, l0, c0, emb0, out);
        }
    }
}

// ---------------------------------------------------------------------------
extern "C" void kernel_launch(void* const* d_in, const int* in_sizes, int n_in,
                              void* d_out, int out_size, void* d_ws, size_t ws_size,
                              hipStream_t stream)
{
    const int*   ids   = (const int*)  d_in[0];
    const float* emb0  = (const float*)d_in[1];
    const float* emb1  = (const float*)d_in[2];
    const float* emb2  = (const float*)d_in[3];
    const float* proj1 = (const float*)d_in[4];
    const float* proj2 = (const float*)d_in[5];
    float*       out   = (float*)d_out;
    const int n = in_sizes[0];                 // 32768 tokens

    // ws layout: [0,256) counters | l0,l1,l2 (n int2 each) | p1bf | p2bf
    int*   cnt  = (int*)d_ws;
    int2v* l0   = (int2v*)((char*)d_ws + 256);
    int2v* l1   = l0 + n;
    int2v* l2   = l1 + n;
    size_t poff = (256 + (size_t)3 * n * 8 + 255) & ~(size_t)255;
    short8* p1bf = (short8*)((char*)d_ws + poff);
    short8* p2bf = p1bf + 32768;               // p1: 32768 frags (512 KB)

    const int pb = (n + 1023) / 1024;          // partition blocks (1024 thr)

    hipMemsetAsync(cnt, 0, 4 * sizeof(int), stream);
    prep_k<<<pb + 32 + 8, 1024, 0, stream>>>(ids, n, pb, cnt, l0, l1, l2,
                                             proj1, proj2, p1bf, p2bf);
    fused_main<<<2048, 512, 0, stream>>>(emb0, emb1, emb2,
                                         p1bf, p2bf, l0, l1, l2, cnt, out);
}